// Round 1
// baseline (52.815 us; speedup 1.0000x reference)
//
#include <hip/hip_runtime.h>

// Problem constants (from reference): V=50000, F=100000, H=W=256, K=1, B=4, J=256
#define HH    256
#define WW    256
#define NPIX  (HH * WW)          // 65536
#define BB    4
#define JJ    256

// Output layout (concatenated flat, fp32):
//   colors  : (B,H,W,3)  base 0            size 786432
//   diffuse : (B,H,W,3)  base 786432       size 786432
//   texels  : (1,H,W,3)  base 1572864      size 196608
//   normals : (B,H,W,3)  base 1769472      size 786432

__global__ __launch_bounds__(256) void shade_kernel(
    const int*   __restrict__ p2f,    // (1,H,W,1) int32
    const float* __restrict__ bary,   // (1,H,W,1,3)
    const int*   __restrict__ faces,  // (F,3)
    const float* __restrict__ vnorm,  // (V,3)
    const float* __restrict__ dirs,   // (B,J,3)
    const float* __restrict__ env,    // (B,J,3)
    const float* __restrict__ tex,    // (1,H,W,3)
    float*       __restrict__ out)
{
    const int t = blockIdx.x * 256 + threadIdx.x;   // 0 .. B*NPIX-1
    const int b = t >> 16;                          // t / NPIX  (uniform per block)
    const int p = t & (NPIX - 1);                   // pixel index

    // ---- per-pixel normal (gather + barycentric blend + normalize) ----
    const int f  = p2f[p];
    const int v0 = faces[3*f + 0];
    const int v1 = faces[3*f + 1];
    const int v2 = faces[3*f + 2];
    const float b0 = bary[3*p + 0];
    const float b1 = bary[3*p + 1];
    const float b2 = bary[3*p + 2];

    float nx = b0 * vnorm[3*v0 + 0] + b1 * vnorm[3*v1 + 0] + b2 * vnorm[3*v2 + 0];
    float ny = b0 * vnorm[3*v0 + 1] + b1 * vnorm[3*v1 + 1] + b2 * vnorm[3*v2 + 1];
    float nz = b0 * vnorm[3*v0 + 2] + b1 * vnorm[3*v1 + 2] + b2 * vnorm[3*v2 + 2];

    const float nrm = fmaxf(sqrtf(nx*nx + ny*ny + nz*nz), 1e-6f);
    const float inv = 1.0f / nrm;
    nx *= inv; ny *= inv; nz *= inv;

    // ---- accumulate over J lights for this batch b ----
    float ar = 0.f, ag = 0.f, ab = 0.f;
    const float* __restrict__ dp = dirs + b * JJ * 3;
    const float* __restrict__ ep = env  + b * JJ * 3;

    #pragma unroll 4
    for (int j = 0; j < JJ; ++j) {
        const float dx = dp[3*j + 0];
        const float dy = dp[3*j + 1];
        const float dz = dp[3*j + 2];
        float w = nx*dx + ny*dy + nz*dz;
        w = fminf(fmaxf(w, 0.f), 1.f);          // clip to [0,1]
        ar = fmaf(ep[3*j + 0], w, ar);
        ag = fmaf(ep[3*j + 1], w, ag);
        ab = fmaf(ep[3*j + 2], w, ab);
    }

    // ---- outputs ----
    const float tr = tex[3*p + 0];
    const float tg = tex[3*p + 1];
    const float tb = tex[3*p + 2];

    const int o = 3 * (b * NPIX + p);

    // colors = diffuse * texels
    out[o + 0] = ar * tr;
    out[o + 1] = ag * tg;
    out[o + 2] = ab * tb;

    // diffuse
    float* __restrict__ dif = out + 3 * BB * NPIX;
    dif[o + 0] = ar;
    dif[o + 1] = ag;
    dif[o + 2] = ab;

    // normals (broadcast of pixel normal over B)
    float* __restrict__ nor = out + 3 * BB * NPIX * 2 + 3 * NPIX;
    nor[o + 0] = nx;
    nor[o + 1] = ny;
    nor[o + 2] = nz;

    // texels passthrough (only batch-0 threads write; b is block-uniform)
    if (b == 0) {
        float* __restrict__ tx = out + 3 * BB * NPIX * 2;
        tx[3*p + 0] = tr;
        tx[3*p + 1] = tg;
        tx[3*p + 2] = tb;
    }
}

extern "C" void kernel_launch(void* const* d_in, const int* in_sizes, int n_in,
                              void* d_out, int out_size, void* d_ws, size_t ws_size,
                              hipStream_t stream) {
    const int*   p2f   = (const int*)  d_in[0];
    const float* bary  = (const float*)d_in[1];
    const int*   faces = (const int*)  d_in[2];
    // d_in[3] = verts (unused by the reference computation)
    const float* vnorm = (const float*)d_in[4];
    const float* dirs  = (const float*)d_in[5];
    const float* env   = (const float*)d_in[6];
    const float* tex   = (const float*)d_in[7];
    float* out = (float*)d_out;

    const int total = BB * NPIX;                 // 262144 threads
    shade_kernel<<<total / 256, 256, 0, stream>>>(
        p2f, bary, faces, vnorm, dirs, env, tex, out);
}

// Round 3
// 22.030 us; speedup vs baseline: 2.3975x; 2.3975x over previous
//
#include <hip/hip_runtime.h>

// Problem constants (from reference): V=50000, F=100000, H=W=256, K=1, B=4, J=256
#define HH    256
#define WW    256
#define NPIX  (HH * WW)          // 65536
#define BB    4
#define JJ    256

// Output layout (concatenated flat, fp32):
//   colors  : (B,H,W,3)  base 0            size 786432
//   diffuse : (B,H,W,3)  base 786432       size 786432
//   texels  : (1,H,W,3)  base 1572864      size 196608
//   normals : (B,H,W,3)  base 1769472      size 786432

// Grid mapping: blockIdx.x in [0,1024); b = blockIdx.x>>8 (COMPILE-TIME uniform
// -> light addresses are wave-uniform -> compiler emits s_load for dirs/env).
__global__ __launch_bounds__(256) void shade_kernel(
    const int*   __restrict__ p2f,    // (1,H,W,1) int32
    const float* __restrict__ bary,   // (1,H,W,1,3)
    const int*   __restrict__ faces,  // (F,3)
    const float* __restrict__ vnorm,  // (V,3)
    const float* __restrict__ dirs,   // (B,J,3)
    const float* __restrict__ env,    // (B,J,3)
    const float* __restrict__ tex,    // (1,H,W,3)
    float*       __restrict__ out)
{
    const int b = blockIdx.x >> 8;                         // batch: block-uniform by construction
    const int p = ((blockIdx.x & 255) << 8) | threadIdx.x; // pixel index 0..65535

    // ---- per-pixel normal (gather + barycentric blend + normalize) ----
    const int f  = p2f[p];
    const int v0 = faces[3*f + 0];
    const int v1 = faces[3*f + 1];
    const int v2 = faces[3*f + 2];
    const float b0 = bary[3*p + 0];
    const float b1 = bary[3*p + 1];
    const float b2 = bary[3*p + 2];

    float nx = b0 * vnorm[3*v0 + 0] + b1 * vnorm[3*v1 + 0] + b2 * vnorm[3*v2 + 0];
    float ny = b0 * vnorm[3*v0 + 1] + b1 * vnorm[3*v1 + 1] + b2 * vnorm[3*v2 + 1];
    float nz = b0 * vnorm[3*v0 + 2] + b1 * vnorm[3*v1 + 2] + b2 * vnorm[3*v2 + 2];

    const float nrm = fmaxf(sqrtf(nx*nx + ny*ny + nz*nz), 1e-6f);
    const float inv = 1.0f / nrm;
    nx *= inv; ny *= inv; nz *= inv;

    // ---- accumulate over J lights for this batch (uniform scalar loads) ----
    float ar = 0.f, ag = 0.f, ab = 0.f;
    const float* __restrict__ dp = dirs + b * (JJ * 3);
    const float* __restrict__ ep = env  + b * (JJ * 3);

    #pragma unroll 8
    for (int j = 0; j < JJ; ++j) {
        const float dx = dp[3*j + 0];
        const float dy = dp[3*j + 1];
        const float dz = dp[3*j + 2];
        float w = fmaf(nz, dz, fmaf(ny, dy, nx * dx));
        w = fminf(fmaxf(w, 0.f), 1.f);          // -> v_med3_f32
        ar = fmaf(ep[3*j + 0], w, ar);
        ag = fmaf(ep[3*j + 1], w, ag);
        ab = fmaf(ep[3*j + 2], w, ab);
    }

    // ---- outputs ----
    const float tr = tex[3*p + 0];
    const float tg = tex[3*p + 1];
    const float tb = tex[3*p + 2];

    const int o = 3 * (b * NPIX + p);

    // colors = diffuse * texels
    out[o + 0] = ar * tr;
    out[o + 1] = ag * tg;
    out[o + 2] = ab * tb;

    // diffuse
    float* __restrict__ dif = out + 3 * BB * NPIX;
    dif[o + 0] = ar;
    dif[o + 1] = ag;
    dif[o + 2] = ab;

    // normals (broadcast of pixel normal over B)
    float* __restrict__ nor = out + 3 * BB * NPIX * 2 + 3 * NPIX;
    nor[o + 0] = nx;
    nor[o + 1] = ny;
    nor[o + 2] = nz;

    // texels passthrough (batch-0 blocks only; b is block-uniform)
    if (b == 0) {
        float* __restrict__ tx = out + 3 * BB * NPIX * 2;
        tx[3*p + 0] = tr;
        tx[3*p + 1] = tg;
        tx[3*p + 2] = tb;
    }
}

extern "C" void kernel_launch(void* const* d_in, const int* in_sizes, int n_in,
                              void* d_out, int out_size, void* d_ws, size_t ws_size,
                              hipStream_t stream) {
    const int*   p2f   = (const int*)  d_in[0];
    const float* bary  = (const float*)d_in[1];
    const int*   faces = (const int*)  d_in[2];
    // d_in[3] = verts (unused by the reference computation)
    const float* vnorm = (const float*)d_in[4];
    const float* dirs  = (const float*)d_in[5];
    const float* env   = (const float*)d_in[6];
    const float* tex   = (const float*)d_in[7];
    float* out = (float*)d_out;

    const int grid = BB * (NPIX / 256);   // 4 * 256 = 1024 blocks
    shade_kernel<<<grid, 256, 0, stream>>>(
        p2f, bary, faces, vnorm, dirs, env, tex, out);
}